// Round 1
// baseline (1581.317 us; speedup 1.0000x reference)
//
#include <hip/hip_runtime.h>
#include <hip/hip_bf16.h>
#include <math.h>

#define NEG_SLOPE 0.2f
#define BN_EPS 1e-5f

__device__ __forceinline__ void atomAddF(float* p, float v) { unsafeAtomicAdd(p, v); }

// Monotone float->uint key: unsigned compare order == float order
__device__ __forceinline__ unsigned fkey(float f) {
    unsigned b = __float_as_uint(f);
    return (b & 0x80000000u) ? ~b : (b | 0x80000000u);
}
__device__ __forceinline__ float fdecode(unsigned k) {
    unsigned b = (k & 0x80000000u) ? (k & 0x7FFFFFFFu) : ~k;
    return __uint_as_float(b);
}

// ---------------- GEMM: C[M,N] = A[M,K] @ B[K,N], fp32, 64x64 tile ----------------
__global__ __launch_bounds__(256) void gemm_kernel(const float* __restrict__ A,
                                                   const float* __restrict__ B,
                                                   float* __restrict__ C,
                                                   int M, int N, int K) {
    __shared__ float As[16][65];  // +1 pad: transposed stores
    __shared__ float Bs[16][64];
    const int tid = threadIdx.x;
    const int bm = blockIdx.y * 64;
    const int bn = blockIdx.x * 64;
    const int tm = (tid >> 4) * 4;
    const int tn = (tid & 15) * 4;
    const int arow = tid >> 2;         // 0..63
    const int akv  = (tid & 3) * 4;    // 0,4,8,12
    const int bkr  = tid >> 4;         // 0..15
    const int bnv  = (tid & 15) * 4;   // 0..60
    const int gr = bm + arow;
    float acc[4][4] = {};
    for (int k0 = 0; k0 < K; k0 += 16) {
        float4 av = make_float4(0.f, 0.f, 0.f, 0.f);
        if (gr < M) av = *(const float4*)(A + (size_t)gr * K + k0 + akv);
        As[akv + 0][arow] = av.x; As[akv + 1][arow] = av.y;
        As[akv + 2][arow] = av.z; As[akv + 3][arow] = av.w;
        *(float4*)(&Bs[bkr][bnv]) = *(const float4*)(B + (size_t)(k0 + bkr) * N + bn + bnv);
        __syncthreads();
#pragma unroll
        for (int kk = 0; kk < 16; ++kk) {
            float a0 = As[kk][tm + 0], a1 = As[kk][tm + 1];
            float a2 = As[kk][tm + 2], a3 = As[kk][tm + 3];
            float b0 = Bs[kk][tn + 0], b1 = Bs[kk][tn + 1];
            float b2 = Bs[kk][tn + 2], b3 = Bs[kk][tn + 3];
            acc[0][0] += a0 * b0; acc[0][1] += a0 * b1; acc[0][2] += a0 * b2; acc[0][3] += a0 * b3;
            acc[1][0] += a1 * b0; acc[1][1] += a1 * b1; acc[1][2] += a1 * b2; acc[1][3] += a1 * b3;
            acc[2][0] += a2 * b0; acc[2][1] += a2 * b1; acc[2][2] += a2 * b2; acc[2][3] += a2 * b3;
            acc[3][0] += a3 * b0; acc[3][1] += a3 * b1; acc[3][2] += a3 * b2; acc[3][3] += a3 * b3;
        }
        __syncthreads();
    }
#pragma unroll
    for (int i = 0; i < 4; ++i) {
        int r = bm + tm + i;
        if (r < M)
            *(float4*)(C + (size_t)r * N + bn + tn) =
                make_float4(acc[i][0], acc[i][1], acc[i][2], acc[i][3]);
    }
}

// ---------------- Layer 1 scores: s_src/s_dst per (node, head), init m/d ----------
__global__ __launch_bounds__(256) void score1_kernel(const float* __restrict__ h1,
                                                     const float* __restrict__ asrc,
                                                     const float* __restrict__ adst,
                                                     float* __restrict__ ssrc,
                                                     float* __restrict__ sdst,
                                                     unsigned* __restrict__ mkey,
                                                     float* __restrict__ den) {
    const int n = blockIdx.x;
    const int tid = threadIdx.x;       // == h*64 + c
    float v = h1[(size_t)n * 256 + tid];
    float ps = v * asrc[tid];
    float pd = v * adst[tid];
#pragma unroll
    for (int o = 32; o; o >>= 1) { ps += __shfl_down(ps, o); pd += __shfl_down(pd, o); }
    const int lane = tid & 63, w = tid >> 6;
    if (lane == 0) {
        ssrc[n * 4 + w] = ps;
        sdst[n * 4 + w] = pd;
        mkey[n * 4 + w] = 0u;    // fkey-space -inf
        den[n * 4 + w] = 0.f;
    }
}

// ---------------- Layer 1 edge passes ----------------
__global__ __launch_bounds__(256) void emax1_kernel(const int* __restrict__ src,
                                                    const int* __restrict__ dst,
                                                    const float* __restrict__ ssrc,
                                                    const float* __restrict__ sdst,
                                                    unsigned* __restrict__ mkey,
                                                    int E, int Etot) {
    int e = blockIdx.x * blockDim.x + threadIdx.x;
    if (e >= Etot) return;
    int s, d;
    if (e < E) { s = src[e]; d = dst[e]; } else { s = d = e - E; }
    float4 a = *(const float4*)(ssrc + (size_t)s * 4);
    float4 b = *(const float4*)(sdst + (size_t)d * 4);
    float el[4] = { a.x + b.x, a.y + b.y, a.z + b.z, a.w + b.w };
#pragma unroll
    for (int h = 0; h < 4; ++h) {
        float v = el[h];
        v = v > 0.f ? v : NEG_SLOPE * v;
        atomicMax(mkey + (size_t)d * 4 + h, fkey(v));
    }
}

__global__ __launch_bounds__(256) void esum1_kernel(const int* __restrict__ src,
                                                    const int* __restrict__ dst,
                                                    const float* __restrict__ ssrc,
                                                    const float* __restrict__ sdst,
                                                    const unsigned* __restrict__ mkey,
                                                    float* __restrict__ den,
                                                    float* __restrict__ ex1,
                                                    int E, int Etot) {
    int e = blockIdx.x * blockDim.x + threadIdx.x;
    if (e >= Etot) return;
    int s, d;
    if (e < E) { s = src[e]; d = dst[e]; } else { s = d = e - E; }
    float4 a = *(const float4*)(ssrc + (size_t)s * 4);
    float4 b = *(const float4*)(sdst + (size_t)d * 4);
    uint4 mk = *(const uint4*)(mkey + (size_t)d * 4);
    float el[4] = { a.x + b.x, a.y + b.y, a.z + b.z, a.w + b.w };
    float m[4] = { fdecode(mk.x), fdecode(mk.y), fdecode(mk.z), fdecode(mk.w) };
    float ex[4];
#pragma unroll
    for (int h = 0; h < 4; ++h) {
        float v = el[h];
        v = v > 0.f ? v : NEG_SLOPE * v;
        ex[h] = expf(v - m[h]);
        atomAddF(den + (size_t)d * 4 + h, ex[h]);
    }
    *(float4*)(ex1 + (size_t)e * 4) = make_float4(ex[0], ex[1], ex[2], ex[3]);
}

// one wave per edge: lane = channel within head, 4 heads
__global__ __launch_bounds__(256) void agg1_kernel(const int* __restrict__ src,
                                                   const int* __restrict__ dst,
                                                   const float* __restrict__ ex1,
                                                   const float* __restrict__ den,
                                                   const float* __restrict__ h1,
                                                   float* __restrict__ out1,
                                                   int E, int Etot) {
    int w = (blockIdx.x * blockDim.x + threadIdx.x) >> 6;
    int lane = threadIdx.x & 63;
    if (w >= Etot) return;
    int s, d;
    if (w < E) { s = src[w]; d = dst[w]; } else { s = d = w - E; }
    float4 ex = *(const float4*)(ex1 + (size_t)w * 4);
    float4 dn = *(const float4*)(den + (size_t)d * 4);
    float al[4] = { ex.x / (dn.x + 1e-16f), ex.y / (dn.y + 1e-16f),
                    ex.z / (dn.z + 1e-16f), ex.w / (dn.w + 1e-16f) };
    const float* hs = h1 + (size_t)s * 256;
    float* od = out1 + (size_t)d * 256;
#pragma unroll
    for (int h = 0; h < 4; ++h)
        atomAddF(od + h * 64 + lane, al[h] * hs[h * 64 + lane]);
}

// ---------------- BN (eval) + bias + ELU, in place, vectorized ----------------
__global__ __launch_bounds__(256) void bnelu_kernel(float* __restrict__ x,
                                                    const float* __restrict__ b,
                                                    const float* __restrict__ g,
                                                    const float* __restrict__ be,
                                                    const float* __restrict__ rm,
                                                    const float* __restrict__ rv,
                                                    int nvec, int cmask) {
    int i = blockIdx.x * blockDim.x + threadIdx.x;
    if (i >= nvec) return;
    int c = (i * 4) & cmask;
    float4 v = ((const float4*)x)[i];
    float4 bb = *(const float4*)(b + c), gg = *(const float4*)(g + c);
    float4 ee = *(const float4*)(be + c), mm = *(const float4*)(rm + c);
    float4 vv = *(const float4*)(rv + c);
    v.x = (v.x + bb.x - mm.x) * rsqrtf(vv.x + BN_EPS) * gg.x + ee.x;
    v.y = (v.y + bb.y - mm.y) * rsqrtf(vv.y + BN_EPS) * gg.y + ee.y;
    v.z = (v.z + bb.z - mm.z) * rsqrtf(vv.z + BN_EPS) * gg.z + ee.z;
    v.w = (v.w + bb.w - mm.w) * rsqrtf(vv.w + BN_EPS) * gg.w + ee.w;
    v.x = v.x > 0.f ? v.x : expm1f(v.x);
    v.y = v.y > 0.f ? v.y : expm1f(v.y);
    v.z = v.z > 0.f ? v.z : expm1f(v.z);
    v.w = v.w > 0.f ? v.w : expm1f(v.w);
    ((float4*)x)[i] = v;
}

// ---------------- Layer 2 scores (1 head, 128 ch): 4 nodes/block ----------------
__global__ __launch_bounds__(256) void score2_kernel(const float* __restrict__ h2,
                                                     const float* __restrict__ asrc,
                                                     const float* __restrict__ adst,
                                                     float* __restrict__ ssrc,
                                                     float* __restrict__ sdst,
                                                     unsigned* __restrict__ mkey,
                                                     float* __restrict__ den) {
    const int n = blockIdx.x * 4 + (threadIdx.x >> 6);
    const int lane = threadIdx.x & 63;
    float v0 = h2[(size_t)n * 128 + lane];
    float v1 = h2[(size_t)n * 128 + 64 + lane];
    float ps = v0 * asrc[lane] + v1 * asrc[64 + lane];
    float pd = v0 * adst[lane] + v1 * adst[64 + lane];
#pragma unroll
    for (int o = 32; o; o >>= 1) { ps += __shfl_down(ps, o); pd += __shfl_down(pd, o); }
    if (lane == 0) {
        ssrc[n] = ps; sdst[n] = pd; mkey[n] = 0u; den[n] = 0.f;
    }
}

__global__ __launch_bounds__(256) void emax2_kernel(const int* __restrict__ src,
                                                    const int* __restrict__ dst,
                                                    const float* __restrict__ ssrc,
                                                    const float* __restrict__ sdst,
                                                    unsigned* __restrict__ mkey,
                                                    int E, int Etot) {
    int e = blockIdx.x * blockDim.x + threadIdx.x;
    if (e >= Etot) return;
    int s, d;
    if (e < E) { s = src[e]; d = dst[e]; } else { s = d = e - E; }
    float v = ssrc[s] + sdst[d];
    v = v > 0.f ? v : NEG_SLOPE * v;
    atomicMax(mkey + d, fkey(v));
}

__global__ __launch_bounds__(256) void esum2_kernel(const int* __restrict__ src,
                                                    const int* __restrict__ dst,
                                                    const float* __restrict__ ssrc,
                                                    const float* __restrict__ sdst,
                                                    const unsigned* __restrict__ mkey,
                                                    float* __restrict__ den,
                                                    float* __restrict__ ex2,
                                                    int E, int Etot) {
    int e = blockIdx.x * blockDim.x + threadIdx.x;
    if (e >= Etot) return;
    int s, d;
    if (e < E) { s = src[e]; d = dst[e]; } else { s = d = e - E; }
    float v = ssrc[s] + sdst[d];
    v = v > 0.f ? v : NEG_SLOPE * v;
    float ex = expf(v - fdecode(mkey[d]));
    ex2[e] = ex;
    atomAddF(den + d, ex);
}

__global__ __launch_bounds__(256) void agg2_kernel(const int* __restrict__ src,
                                                   const int* __restrict__ dst,
                                                   const float* __restrict__ ex2,
                                                   const float* __restrict__ den,
                                                   const float* __restrict__ h2,
                                                   float* __restrict__ out2,
                                                   int E, int Etot) {
    int w = (blockIdx.x * blockDim.x + threadIdx.x) >> 6;
    int lane = threadIdx.x & 63;
    if (w >= Etot) return;
    int s, d;
    if (w < E) { s = src[w]; d = dst[w]; } else { s = d = w - E; }
    float al = ex2[w] / (den[d] + 1e-16f);
    const float* hs = h2 + (size_t)s * 128;
    float* od = out2 + (size_t)d * 128;
    atomAddF(od + lane, al * hs[lane]);
    atomAddF(od + 64 + lane, al * hs[64 + lane]);
}

// ---------------- pooling ----------------
__global__ __launch_bounds__(256) void cnt_kernel(const int* __restrict__ batch,
                                                  int* __restrict__ cnt, int N) {
    int i = blockIdx.x * blockDim.x + threadIdx.x;
    if (i < N) atomicAdd(cnt + batch[i], 1);
}

// thread j = channel; block = run of nodes; BN2 fused; run-length atomics per graph
__global__ __launch_bounds__(128) void pool_kernel(const float* __restrict__ out2,
                                                   const int* __restrict__ batch,
                                                   const float* __restrict__ b,
                                                   const float* __restrict__ g,
                                                   const float* __restrict__ be,
                                                   const float* __restrict__ rm,
                                                   const float* __restrict__ rv,
                                                   float* __restrict__ pool,
                                                   int N, int npb) {
    const int j = threadIdx.x;
    int n0 = blockIdx.x * npb;
    int n1 = min(n0 + npb, N);
    if (n0 >= n1) return;
    const float bj = b[j], bej = be[j], rmj = rm[j];
    const float sc = rsqrtf(rv[j] + BN_EPS) * g[j];
    int curg = batch[n0];
    float acc = 0.f;
    for (int n = n0; n < n1; ++n) {
        int gr = batch[n];
        if (gr != curg) {
            atomAddF(pool + (size_t)curg * 128 + j, acc);
            acc = 0.f; curg = gr;
        }
        float x = out2[(size_t)n * 128 + j];
        acc += (x + bj - rmj) * sc + bej;
    }
    atomAddF(pool + (size_t)curg * 128 + j, acc);
}

__global__ __launch_bounds__(256) void final_kernel(const float* __restrict__ pool,
                                                    const int* __restrict__ cnt,
                                                    float* __restrict__ out) {
    int i = blockIdx.x * blockDim.x + threadIdx.x;  // 0..2047
    int g = i >> 7;
    out[i] = pool[i] / fmaxf((float)cnt[g], 1.f);
}

extern "C" void kernel_launch(void* const* d_in, const int* in_sizes, int n_in,
                              void* d_out, int out_size, void* d_ws, size_t ws_size,
                              hipStream_t stream) {
    const float* x    = (const float*)d_in[0];
    const int* ei     = (const int*)d_in[1];
    const int* batch  = (const int*)d_in[2];
    const float* W1   = (const float*)d_in[3];
    const float* as1  = (const float*)d_in[4];
    const float* ad1  = (const float*)d_in[5];
    const float* b1   = (const float*)d_in[6];
    const float* g1   = (const float*)d_in[7];
    const float* be1  = (const float*)d_in[8];
    const float* rm1  = (const float*)d_in[9];
    const float* rv1  = (const float*)d_in[10];
    const float* W2   = (const float*)d_in[11];
    const float* as2  = (const float*)d_in[12];
    const float* ad2  = (const float*)d_in[13];
    const float* b2   = (const float*)d_in[14];
    const float* g2   = (const float*)d_in[15];
    const float* be2  = (const float*)d_in[16];
    const float* rm2  = (const float*)d_in[17];
    const float* rv2  = (const float*)d_in[18];
    float* out = (float*)d_out;

    const int N = in_sizes[0] / 128;   // 20000
    const int E = in_sizes[1] / 2;     // 640000
    const int Etot = E + N;            // 660000 (self-loops appended)
    const int* src = ei;
    const int* dst = ei + E;

    // workspace layout (floats); h2/out2 alias h1's region (h1 dead after agg1)
    float* ws    = (float*)d_ws;
    float* h1    = ws;                               // N*256
    float* out1  = h1 + (size_t)N * 256;             // N*256
    float* ssrc1 = out1 + (size_t)N * 256;           // N*4
    float* sdst1 = ssrc1 + (size_t)N * 4;            // N*4
    unsigned* m1 = (unsigned*)(sdst1 + (size_t)N * 4); // N*4
    float* d1    = (float*)m1 + (size_t)N * 4;       // N*4
    float* ex1   = d1 + (size_t)N * 4;               // Etot*4
    float* ssrc2 = ex1 + (size_t)Etot * 4;           // N
    float* sdst2 = ssrc2 + N;                        // N
    unsigned* m2 = (unsigned*)(sdst2 + N);           // N
    float* d2    = (float*)m2 + N;                   // N
    float* ex2   = d2 + N;                           // Etot
    float* pool  = ex2 + Etot;                       // 16*128
    int*   cnt   = (int*)(pool + 2048);              // 16
    float* h2    = ws;                               // N*128 (aliases h1)
    float* out2  = ws + (size_t)N * 128;             // N*128 (aliases h1 upper half)

    hipMemsetAsync(out1, 0, (size_t)N * 256 * sizeof(float), stream);
    hipMemsetAsync(pool, 0, (2048 + 16) * sizeof(float), stream);  // pool + cnt

    const int eb = (Etot + 255) / 256;

    // ---- layer 1 ----
    gemm_kernel<<<dim3(256 / 64, (N + 63) / 64), 256, 0, stream>>>(x, W1, h1, N, 256, 128);
    score1_kernel<<<N, 256, 0, stream>>>(h1, as1, ad1, ssrc1, sdst1, m1, d1);
    emax1_kernel<<<eb, 256, 0, stream>>>(src, dst, ssrc1, sdst1, m1, E, Etot);
    esum1_kernel<<<eb, 256, 0, stream>>>(src, dst, ssrc1, sdst1, m1, d1, ex1, E, Etot);
    agg1_kernel<<<(Etot + 3) / 4, 256, 0, stream>>>(src, dst, ex1, d1, h1, out1, E, Etot);
    bnelu_kernel<<<((N * 64) + 255) / 256, 256, 0, stream>>>(out1, b1, g1, be1, rm1, rv1,
                                                             N * 64, 255);
    // ---- layer 2 (h1 region now dead; reuse for h2/out2) ----
    gemm_kernel<<<dim3(128 / 64, (N + 63) / 64), 256, 0, stream>>>(out1, W2, h2, N, 128, 256);
    hipMemsetAsync(out2, 0, (size_t)N * 128 * sizeof(float), stream);
    score2_kernel<<<N / 4, 256, 0, stream>>>(h2, as2, ad2, ssrc2, sdst2, m2, d2);
    emax2_kernel<<<eb, 256, 0, stream>>>(src, dst, ssrc2, sdst2, m2, E, Etot);
    esum2_kernel<<<eb, 256, 0, stream>>>(src, dst, ssrc2, sdst2, m2, d2, ex2, E, Etot);
    agg2_kernel<<<(Etot + 3) / 4, 256, 0, stream>>>(src, dst, ex2, d2, h2, out2, E, Etot);

    // ---- pool ----
    cnt_kernel<<<(N + 255) / 256, 256, 0, stream>>>(batch, cnt, N);
    pool_kernel<<<(N + 159) / 160, 128, 0, stream>>>(out2, batch, b2, g2, be2, rm2, rv2,
                                                     pool, N, 160);
    final_kernel<<<8, 256, 0, stream>>>(pool, cnt, out);
}

// Round 2
// 793.021 us; speedup vs baseline: 1.9940x; 1.9940x over previous
//
#include <hip/hip_runtime.h>
#include <hip/hip_bf16.h>
#include <math.h>

#define NEG_SLOPE 0.2f
#define BN_EPS 1e-5f

__device__ __forceinline__ void atomAddF(float* p, float v) { unsafeAtomicAdd(p, v); }

// ---------------- GEMM: C[M,N] = A[M,K] @ B[K,N], fp32, 64x64 tile ----------------
__global__ __launch_bounds__(256) void gemm_kernel(const float* __restrict__ A,
                                                   const float* __restrict__ B,
                                                   float* __restrict__ C,
                                                   int M, int N, int K) {
    __shared__ float As[16][65];  // +1 pad: transposed stores
    __shared__ float Bs[16][64];
    const int tid = threadIdx.x;
    const int bm = blockIdx.y * 64;
    const int bn = blockIdx.x * 64;
    const int tm = (tid >> 4) * 4;
    const int tn = (tid & 15) * 4;
    const int arow = tid >> 2;         // 0..63
    const int akv  = (tid & 3) * 4;    // 0,4,8,12
    const int bkr  = tid >> 4;         // 0..15
    const int bnv  = (tid & 15) * 4;   // 0..60
    const int gr = bm + arow;
    float acc[4][4] = {};
    for (int k0 = 0; k0 < K; k0 += 16) {
        float4 av = make_float4(0.f, 0.f, 0.f, 0.f);
        if (gr < M) av = *(const float4*)(A + (size_t)gr * K + k0 + akv);
        As[akv + 0][arow] = av.x; As[akv + 1][arow] = av.y;
        As[akv + 2][arow] = av.z; As[akv + 3][arow] = av.w;
        *(float4*)(&Bs[bkr][bnv]) = *(const float4*)(B + (size_t)(k0 + bkr) * N + bn + bnv);
        __syncthreads();
#pragma unroll
        for (int kk = 0; kk < 16; ++kk) {
            float a0 = As[kk][tm + 0], a1 = As[kk][tm + 1];
            float a2 = As[kk][tm + 2], a3 = As[kk][tm + 3];
            float b0 = Bs[kk][tn + 0], b1 = Bs[kk][tn + 1];
            float b2 = Bs[kk][tn + 2], b3 = Bs[kk][tn + 3];
            acc[0][0] += a0 * b0; acc[0][1] += a0 * b1; acc[0][2] += a0 * b2; acc[0][3] += a0 * b3;
            acc[1][0] += a1 * b0; acc[1][1] += a1 * b1; acc[1][2] += a1 * b2; acc[1][3] += a1 * b3;
            acc[2][0] += a2 * b0; acc[2][1] += a2 * b1; acc[2][2] += a2 * b2; acc[2][3] += a2 * b3;
            acc[3][0] += a3 * b0; acc[3][1] += a3 * b1; acc[3][2] += a3 * b2; acc[3][3] += a3 * b3;
        }
        __syncthreads();
    }
#pragma unroll
    for (int i = 0; i < 4; ++i) {
        int r = bm + tm + i;
        if (r < M)
            *(float4*)(C + (size_t)r * N + bn + tn) =
                make_float4(acc[i][0], acc[i][1], acc[i][2], acc[i][3]);
    }
}

// ---------------- CSR build ----------------
__global__ __launch_bounds__(256) void deg_kernel(const int* __restrict__ dst,
                                                  int* __restrict__ deg, int E, int Etot) {
    int e = blockIdx.x * blockDim.x + threadIdx.x;
    if (e >= Etot) return;
    int d = (e < E) ? dst[e] : e - E;
    atomicAdd(deg + d, 1);
}

// single-block exclusive scan over N (<= ~64k), writes rowptr[0..N] and cursor copy
__global__ __launch_bounds__(256) void scan_kernel(const int* __restrict__ deg,
                                                   int* __restrict__ rowptr,
                                                   int* __restrict__ cursor, int N) {
    __shared__ int sums[256];
    const int t = threadIdx.x;
    const int chunk = (N + 255) / 256;
    const int s0 = t * chunk, s1 = min(s0 + chunk, N);
    int sum = 0;
    for (int i = s0; i < s1; ++i) sum += deg[i];
    sums[t] = sum;
    __syncthreads();
    if (t == 0) {
        int acc = 0;
        for (int i = 0; i < 256; ++i) { int v = sums[i]; sums[i] = acc; acc += v; }
        rowptr[N] = acc;
    }
    __syncthreads();
    int acc = sums[t];
    for (int i = s0; i < s1; ++i) { rowptr[i] = acc; cursor[i] = acc; acc += deg[i]; }
}

__global__ __launch_bounds__(256) void scatter_kernel(const int* __restrict__ src,
                                                      const int* __restrict__ dst,
                                                      int* __restrict__ cursor,
                                                      int* __restrict__ csr_src,
                                                      int E, int Etot) {
    int e = blockIdx.x * blockDim.x + threadIdx.x;
    if (e >= Etot) return;
    int s, d;
    if (e < E) { s = src[e]; d = dst[e]; } else { s = d = e - E; }
    int pos = atomicAdd(cursor + d, 1);
    csr_src[pos] = s;
}

// ---------------- Layer 1 scores: s_src/s_dst per (node, head) ----------
__global__ __launch_bounds__(256) void score1_kernel(const float* __restrict__ h1,
                                                     const float* __restrict__ asrc,
                                                     const float* __restrict__ adst,
                                                     float* __restrict__ ssrc,
                                                     float* __restrict__ sdst) {
    const int n = blockIdx.x;
    const int tid = threadIdx.x;       // == h*64 + c
    float v = h1[(size_t)n * 256 + tid];
    float ps = v * asrc[tid];
    float pd = v * adst[tid];
#pragma unroll
    for (int o = 32; o; o >>= 1) { ps += __shfl_down(ps, o); pd += __shfl_down(pd, o); }
    const int lane = tid & 63, w = tid >> 6;
    if (lane == 0) { ssrc[n * 4 + w] = ps; sdst[n * 4 + w] = pd; }
}

// ---------------- Layer 1 fused: softmax + aggregate + bias + BN + ELU ----------
// block = dst node, tid = h*64 + lane; wave h handles head h
__global__ __launch_bounds__(256) void fused1_kernel(const int* __restrict__ csr_src,
                                                     const int* __restrict__ rowptr,
                                                     const float* __restrict__ ssrc,
                                                     const float* __restrict__ sdst,
                                                     const float* __restrict__ h1,
                                                     const float* __restrict__ b,
                                                     const float* __restrict__ g,
                                                     const float* __restrict__ be,
                                                     const float* __restrict__ rm,
                                                     const float* __restrict__ rv,
                                                     float* __restrict__ out1) {
    const int n = blockIdx.x;
    const int tid = threadIdx.x;
    const int h = tid >> 6, lane = tid & 63;
    const int row0 = rowptr[n], row1 = rowptr[n + 1];
    const float sd = sdst[n * 4 + h];

    float m = -1e30f;
    for (int i = row0 + lane; i < row1; i += 64) {
        int s = csr_src[i];
        float sc = ssrc[s * 4 + h] + sd;
        sc = sc > 0.f ? sc : NEG_SLOPE * sc;
        m = fmaxf(m, sc);
    }
#pragma unroll
    for (int o = 32; o; o >>= 1) m = fmaxf(m, __shfl_xor(m, o));

    float den = 0.f;
    for (int i = row0 + lane; i < row1; i += 64) {
        int s = csr_src[i];
        float sc = ssrc[s * 4 + h] + sd;
        sc = sc > 0.f ? sc : NEG_SLOPE * sc;
        den += __expf(sc - m);
    }
#pragma unroll
    for (int o = 32; o; o >>= 1) den += __shfl_xor(den, o);
    const float rden = 1.f / (den + 1e-16f);

    float acc = 0.f;
    for (int i = row0; i < row1; ++i) {
        int s = csr_src[i];                       // wave-uniform → broadcast
        float sc = ssrc[s * 4 + h] + sd;          // same addr across wave → broadcast
        sc = sc > 0.f ? sc : NEG_SLOPE * sc;
        float al = __expf(sc - m) * rden;
        acc += al * h1[(size_t)s * 256 + tid];    // coalesced 1KB row gather
    }
    float v = (acc + b[tid] - rm[tid]) * rsqrtf(rv[tid] + BN_EPS) * g[tid] + be[tid];
    out1[(size_t)n * 256 + tid] = v > 0.f ? v : expm1f(v);
}

// ---------------- Layer 2 scores (1 head, 128 ch): 4 nodes/block ----------------
__global__ __launch_bounds__(256) void score2_kernel(const float* __restrict__ h2,
                                                     const float* __restrict__ asrc,
                                                     const float* __restrict__ adst,
                                                     float* __restrict__ ssrc,
                                                     float* __restrict__ sdst) {
    const int n = blockIdx.x * 4 + (threadIdx.x >> 6);
    const int lane = threadIdx.x & 63;
    float v0 = h2[(size_t)n * 128 + lane];
    float v1 = h2[(size_t)n * 128 + 64 + lane];
    float ps = v0 * asrc[lane] + v1 * asrc[64 + lane];
    float pd = v0 * adst[lane] + v1 * adst[64 + lane];
#pragma unroll
    for (int o = 32; o; o >>= 1) { ps += __shfl_down(ps, o); pd += __shfl_down(pd, o); }
    if (lane == 0) { ssrc[n] = ps; sdst[n] = pd; }
}

// ---------------- Layer 2 fused: softmax + aggregate + bias + BN2 ----------
// block = dst node, 128 threads (2 waves), tid = channel
__global__ __launch_bounds__(128) void fused2_kernel(const int* __restrict__ csr_src,
                                                     const int* __restrict__ rowptr,
                                                     const float* __restrict__ ssrc,
                                                     const float* __restrict__ sdst,
                                                     const float* __restrict__ h2,
                                                     const float* __restrict__ b,
                                                     const float* __restrict__ g,
                                                     const float* __restrict__ be,
                                                     const float* __restrict__ rm,
                                                     const float* __restrict__ rv,
                                                     float* __restrict__ out2) {
    const int n = blockIdx.x;
    const int tid = threadIdx.x;
    const int lane = tid & 63, w = tid >> 6;
    const int row0 = rowptr[n], row1 = rowptr[n + 1];
    const float sd = sdst[n];
    __shared__ float sm[2], sden[2];

    float m = -1e30f;
    for (int i = row0 + tid; i < row1; i += 128) {
        int s = csr_src[i];
        float sc = ssrc[s] + sd;
        sc = sc > 0.f ? sc : NEG_SLOPE * sc;
        m = fmaxf(m, sc);
    }
#pragma unroll
    for (int o = 32; o; o >>= 1) m = fmaxf(m, __shfl_xor(m, o));
    if (lane == 0) sm[w] = m;
    __syncthreads();
    m = fmaxf(sm[0], sm[1]);

    float den = 0.f;
    for (int i = row0 + tid; i < row1; i += 128) {
        int s = csr_src[i];
        float sc = ssrc[s] + sd;
        sc = sc > 0.f ? sc : NEG_SLOPE * sc;
        den += __expf(sc - m);
    }
#pragma unroll
    for (int o = 32; o; o >>= 1) den += __shfl_xor(den, o);
    if (lane == 0) sden[w] = den;
    __syncthreads();
    den = sden[0] + sden[1];
    const float rden = 1.f / (den + 1e-16f);

    float acc = 0.f;
    for (int i = row0; i < row1; ++i) {
        int s = csr_src[i];
        float sc = ssrc[s] + sd;
        sc = sc > 0.f ? sc : NEG_SLOPE * sc;
        acc += __expf(sc - m) * rden * h2[(size_t)s * 128 + tid];
    }
    float v = (acc + b[tid] - rm[tid]) * rsqrtf(rv[tid] + BN_EPS) * g[tid] + be[tid];
    out2[(size_t)n * 128 + tid] = v;   // BN2 applied; no activation
}

// ---------------- pooling ----------------
__global__ __launch_bounds__(256) void cnt_kernel(const int* __restrict__ batch,
                                                  int* __restrict__ cnt, int N) {
    int i = blockIdx.x * blockDim.x + threadIdx.x;
    if (i < N) atomicAdd(cnt + batch[i], 1);
}

// thread j = channel; block = run of nodes; run-length atomics per graph
__global__ __launch_bounds__(128) void pool_kernel(const float* __restrict__ out2,
                                                   const int* __restrict__ batch,
                                                   float* __restrict__ pool,
                                                   int N, int npb) {
    const int j = threadIdx.x;
    int n0 = blockIdx.x * npb;
    int n1 = min(n0 + npb, N);
    if (n0 >= n1) return;
    int curg = batch[n0];
    float acc = 0.f;
    for (int n = n0; n < n1; ++n) {
        int gr = batch[n];
        if (gr != curg) {
            atomAddF(pool + (size_t)curg * 128 + j, acc);
            acc = 0.f; curg = gr;
        }
        acc += out2[(size_t)n * 128 + j];
    }
    atomAddF(pool + (size_t)curg * 128 + j, acc);
}

__global__ __launch_bounds__(256) void final_kernel(const float* __restrict__ pool,
                                                    const int* __restrict__ cnt,
                                                    float* __restrict__ out) {
    int i = blockIdx.x * blockDim.x + threadIdx.x;  // 0..2047
    int g = i >> 7;
    out[i] = pool[i] / fmaxf((float)cnt[g], 1.f);
}

extern "C" void kernel_launch(void* const* d_in, const int* in_sizes, int n_in,
                              void* d_out, int out_size, void* d_ws, size_t ws_size,
                              hipStream_t stream) {
    const float* x    = (const float*)d_in[0];
    const int* ei     = (const int*)d_in[1];
    const int* batch  = (const int*)d_in[2];
    const float* W1   = (const float*)d_in[3];
    const float* as1  = (const float*)d_in[4];
    const float* ad1  = (const float*)d_in[5];
    const float* b1   = (const float*)d_in[6];
    const float* g1   = (const float*)d_in[7];
    const float* be1  = (const float*)d_in[8];
    const float* rm1  = (const float*)d_in[9];
    const float* rv1  = (const float*)d_in[10];
    const float* W2   = (const float*)d_in[11];
    const float* as2  = (const float*)d_in[12];
    const float* ad2  = (const float*)d_in[13];
    const float* b2   = (const float*)d_in[14];
    const float* g2   = (const float*)d_in[15];
    const float* be2  = (const float*)d_in[16];
    const float* rm2  = (const float*)d_in[17];
    const float* rv2  = (const float*)d_in[18];
    float* out = (float*)d_out;

    const int N = in_sizes[0] / 128;   // 20000
    const int E = in_sizes[1] / 2;     // 640000
    const int Etot = E + N;            // self-loops appended
    const int* src = ei;
    const int* dst = ei + E;

    // workspace layout
    float* ws    = (float*)d_ws;
    float* h1    = ws;                               // N*256
    float* out1  = h1 + (size_t)N * 256;             // N*256
    float* out2  = out1 + (size_t)N * 256;           // N*128
    float* ssrc1 = out2 + (size_t)N * 128;           // N*4
    float* sdst1 = ssrc1 + (size_t)N * 4;            // N*4
    float* ssrc2 = sdst1 + (size_t)N * 4;            // N
    float* sdst2 = ssrc2 + N;                        // N
    float* pool  = sdst2 + N;                        // 16*128
    int*   cnt   = (int*)(pool + 2048);              // 16
    int*   deg   = cnt + 16;                         // N
    int*   rowptr= deg + N;                          // N+1
    int*   cursor= rowptr + N + 1;                   // N
    int*   csrs  = cursor + N;                       // Etot
    float* h2    = h1;                               // alias (h1 dead after fused1)

    const int eb = (Etot + 255) / 256;

    hipMemsetAsync(deg, 0, (size_t)N * sizeof(int), stream);
    hipMemsetAsync(pool, 0, (2048 + 16) * sizeof(float), stream);  // pool + cnt

    // ---- CSR build (by dst) ----
    deg_kernel<<<eb, 256, 0, stream>>>(dst, deg, E, Etot);
    scan_kernel<<<1, 256, 0, stream>>>(deg, rowptr, cursor, N);
    scatter_kernel<<<eb, 256, 0, stream>>>(src, dst, cursor, csrs, E, Etot);

    // ---- layer 1 ----
    gemm_kernel<<<dim3(256 / 64, (N + 63) / 64), 256, 0, stream>>>(x, W1, h1, N, 256, 128);
    score1_kernel<<<N, 256, 0, stream>>>(h1, as1, ad1, ssrc1, sdst1);
    fused1_kernel<<<N, 256, 0, stream>>>(csrs, rowptr, ssrc1, sdst1, h1,
                                         b1, g1, be1, rm1, rv1, out1);
    // ---- layer 2 (h1 dead; h2 aliases it) ----
    gemm_kernel<<<dim3(128 / 64, (N + 63) / 64), 256, 0, stream>>>(out1, W2, h2, N, 128, 256);
    score2_kernel<<<N / 4, 256, 0, stream>>>(h2, as2, ad2, ssrc2, sdst2);
    fused2_kernel<<<N, 128, 0, stream>>>(csrs, rowptr, ssrc2, sdst2, h2,
                                         b2, g2, be2, rm2, rv2, out2);

    // ---- pool ----
    cnt_kernel<<<(N + 255) / 256, 256, 0, stream>>>(batch, cnt, N);
    pool_kernel<<<(N + 159) / 160, 128, 0, stream>>>(out2, batch, pool, N, 160);
    final_kernel<<<8, 256, 0, stream>>>(pool, cnt, out);
}

// Round 3
// 579.106 us; speedup vs baseline: 2.7306x; 1.3694x over previous
//
#include <hip/hip_runtime.h>
#include <hip/hip_bf16.h>
#include <math.h>

#define NEG_SLOPE 0.2f
#define BN_EPS 1e-5f

__device__ __forceinline__ void atomAddF(float* p, float v) { unsafeAtomicAdd(p, v); }

// ---------------- GEMM: C[M,N] = A[M,K] @ B[K,N], fp32, 64x64 tile ----------------
__global__ __launch_bounds__(256) void gemm_kernel(const float* __restrict__ A,
                                                   const float* __restrict__ B,
                                                   float* __restrict__ C,
                                                   int M, int N, int K) {
    __shared__ float As[16][65];  // +1 pad: transposed stores
    __shared__ float Bs[16][64];
    const int tid = threadIdx.x;
    const int bm = blockIdx.y * 64;
    const int bn = blockIdx.x * 64;
    const int tm = (tid >> 4) * 4;
    const int tn = (tid & 15) * 4;
    const int arow = tid >> 2;         // 0..63
    const int akv  = (tid & 3) * 4;    // 0,4,8,12
    const int bkr  = tid >> 4;         // 0..15
    const int bnv  = (tid & 15) * 4;   // 0..60
    const int gr = bm + arow;
    float acc[4][4] = {};
    for (int k0 = 0; k0 < K; k0 += 16) {
        float4 av = make_float4(0.f, 0.f, 0.f, 0.f);
        if (gr < M) av = *(const float4*)(A + (size_t)gr * K + k0 + akv);
        As[akv + 0][arow] = av.x; As[akv + 1][arow] = av.y;
        As[akv + 2][arow] = av.z; As[akv + 3][arow] = av.w;
        *(float4*)(&Bs[bkr][bnv]) = *(const float4*)(B + (size_t)(k0 + bkr) * N + bn + bnv);
        __syncthreads();
#pragma unroll
        for (int kk = 0; kk < 16; ++kk) {
            float a0 = As[kk][tm + 0], a1 = As[kk][tm + 1];
            float a2 = As[kk][tm + 2], a3 = As[kk][tm + 3];
            float b0 = Bs[kk][tn + 0], b1 = Bs[kk][tn + 1];
            float b2 = Bs[kk][tn + 2], b3 = Bs[kk][tn + 3];
            acc[0][0] += a0 * b0; acc[0][1] += a0 * b1; acc[0][2] += a0 * b2; acc[0][3] += a0 * b3;
            acc[1][0] += a1 * b0; acc[1][1] += a1 * b1; acc[1][2] += a1 * b2; acc[1][3] += a1 * b3;
            acc[2][0] += a2 * b0; acc[2][1] += a2 * b1; acc[2][2] += a2 * b2; acc[2][3] += a2 * b3;
            acc[3][0] += a3 * b0; acc[3][1] += a3 * b1; acc[3][2] += a3 * b2; acc[3][3] += a3 * b3;
        }
        __syncthreads();
    }
#pragma unroll
    for (int i = 0; i < 4; ++i) {
        int r = bm + tm + i;
        if (r < M)
            *(float4*)(C + (size_t)r * N + bn + tn) =
                make_float4(acc[i][0], acc[i][1], acc[i][2], acc[i][3]);
    }
}

// ---------------- CSR build ----------------
__global__ __launch_bounds__(256) void deg_kernel(const int* __restrict__ dst,
                                                  int* __restrict__ deg, int E, int Etot) {
    int e = blockIdx.x * blockDim.x + threadIdx.x;
    if (e >= Etot) return;
    int d = (e < E) ? dst[e] : e - E;
    atomicAdd(deg + d, 1);
}

// single-block exclusive scan over N, writes rowptr[0..N] and cursor copy
__global__ __launch_bounds__(256) void scan_kernel(const int* __restrict__ deg,
                                                   int* __restrict__ rowptr,
                                                   int* __restrict__ cursor, int N) {
    __shared__ int sums[256];
    const int t = threadIdx.x;
    const int chunk = (N + 255) / 256;
    const int s0 = t * chunk, s1 = min(s0 + chunk, N);
    int sum = 0;
    for (int i = s0; i < s1; ++i) sum += deg[i];
    sums[t] = sum;
    __syncthreads();
    if (t == 0) {
        int acc = 0;
        for (int i = 0; i < 256; ++i) { int v = sums[i]; sums[i] = acc; acc += v; }
        rowptr[N] = acc;
    }
    __syncthreads();
    int acc = sums[t];
    for (int i = s0; i < s1; ++i) { rowptr[i] = acc; cursor[i] = acc; acc += deg[i]; }
}

__global__ __launch_bounds__(256) void scatter_kernel(const int* __restrict__ src,
                                                      const int* __restrict__ dst,
                                                      int* __restrict__ cursor,
                                                      int* __restrict__ csr_src,
                                                      int E, int Etot) {
    int e = blockIdx.x * blockDim.x + threadIdx.x;
    if (e >= Etot) return;
    int s, d;
    if (e < E) { s = src[e]; d = dst[e]; } else { s = d = e - E; }
    int pos = atomicAdd(cursor + d, 1);
    csr_src[pos] = s;
}

// ---------------- Layer 1 scores: s_src/s_dst per (node, head) ----------
__global__ __launch_bounds__(256) void score1_kernel(const float* __restrict__ h1,
                                                     const float* __restrict__ asrc,
                                                     const float* __restrict__ adst,
                                                     float* __restrict__ ssrc,
                                                     float* __restrict__ sdst) {
    const int n = blockIdx.x;
    const int tid = threadIdx.x;       // == h*64 + c
    float v = h1[(size_t)n * 256 + tid];
    float ps = v * asrc[tid];
    float pd = v * adst[tid];
#pragma unroll
    for (int o = 32; o; o >>= 1) { ps += __shfl_down(ps, o); pd += __shfl_down(pd, o); }
    const int lane = tid & 63, w = tid >> 6;
    if (lane == 0) { ssrc[n * 4 + w] = ps; sdst[n * 4 + w] = pd; }
}

// ---------------- Layer 1 fused: softmax + aggregate + bias + BN + ELU ----------
// block = dst node, tid = h*64 + lane; wave h handles head h
__global__ __launch_bounds__(256) void fused1_kernel(const int* __restrict__ csr_src,
                                                     const int* __restrict__ rowptr,
                                                     const float* __restrict__ ssrc,
                                                     const float* __restrict__ sdst,
                                                     const float* __restrict__ h1,
                                                     const float* __restrict__ b,
                                                     const float* __restrict__ g,
                                                     const float* __restrict__ be,
                                                     const float* __restrict__ rm,
                                                     const float* __restrict__ rv,
                                                     float* __restrict__ out1) {
    const int n = blockIdx.x;
    const int tid = threadIdx.x;
    const int h = tid >> 6, lane = tid & 63;
    const int row0 = rowptr[n], row1 = rowptr[n + 1];
    const float sd = sdst[n * 4 + h];

    float m = -1e30f;
    for (int i = row0 + lane; i < row1; i += 64) {
        int s = csr_src[i];
        float sc = ssrc[s * 4 + h] + sd;
        sc = sc > 0.f ? sc : NEG_SLOPE * sc;
        m = fmaxf(m, sc);
    }
#pragma unroll
    for (int o = 32; o; o >>= 1) m = fmaxf(m, __shfl_xor(m, o));

    float den = 0.f;
    for (int i = row0 + lane; i < row1; i += 64) {
        int s = csr_src[i];
        float sc = ssrc[s * 4 + h] + sd;
        sc = sc > 0.f ? sc : NEG_SLOPE * sc;
        den += __expf(sc - m);
    }
#pragma unroll
    for (int o = 32; o; o >>= 1) den += __shfl_xor(den, o);
    const float rden = 1.f / (den + 1e-16f);

    float acc = 0.f;
    for (int i = row0; i < row1; ++i) {
        int s = csr_src[i];                       // wave-uniform → broadcast
        float sc = ssrc[s * 4 + h] + sd;          // same addr across wave → broadcast
        sc = sc > 0.f ? sc : NEG_SLOPE * sc;
        float al = __expf(sc - m) * rden;
        acc += al * h1[(size_t)s * 256 + tid];    // coalesced 1KB row gather
    }
    float v = (acc + b[tid] - rm[tid]) * rsqrtf(rv[tid] + BN_EPS) * g[tid] + be[tid];
    out1[(size_t)n * 256 + tid] = v > 0.f ? v : expm1f(v);
}

// ---------------- Layer 2 scores (1 head, 128 ch): 4 nodes/block ----------------
__global__ __launch_bounds__(256) void score2_kernel(const float* __restrict__ h2,
                                                     const float* __restrict__ asrc,
                                                     const float* __restrict__ adst,
                                                     float* __restrict__ ssrc,
                                                     float* __restrict__ sdst) {
    const int n = blockIdx.x * 4 + (threadIdx.x >> 6);
    const int lane = threadIdx.x & 63;
    float v0 = h2[(size_t)n * 128 + lane];
    float v1 = h2[(size_t)n * 128 + 64 + lane];
    float ps = v0 * asrc[lane] + v1 * asrc[64 + lane];
    float pd = v0 * adst[lane] + v1 * adst[64 + lane];
#pragma unroll
    for (int o = 32; o; o >>= 1) { ps += __shfl_down(ps, o); pd += __shfl_down(pd, o); }
    if (lane == 0) { ssrc[n] = ps; sdst[n] = pd; }
}

// ---------------- Layer 2 fused: softmax + aggregate + bias + BN2 ----------
// block = dst node, 128 threads (2 waves), tid = channel
__global__ __launch_bounds__(128) void fused2_kernel(const int* __restrict__ csr_src,
                                                     const int* __restrict__ rowptr,
                                                     const float* __restrict__ ssrc,
                                                     const float* __restrict__ sdst,
                                                     const float* __restrict__ h2,
                                                     const float* __restrict__ b,
                                                     const float* __restrict__ g,
                                                     const float* __restrict__ be,
                                                     const float* __restrict__ rm,
                                                     const float* __restrict__ rv,
                                                     float* __restrict__ out2) {
    const int n = blockIdx.x;
    const int tid = threadIdx.x;
    const int lane = tid & 63, w = tid >> 6;
    const int row0 = rowptr[n], row1 = rowptr[n + 1];
    const float sd = sdst[n];
    __shared__ float sm[2], sden[2];

    float m = -1e30f;
    for (int i = row0 + tid; i < row1; i += 128) {
        int s = csr_src[i];
        float sc = ssrc[s] + sd;
        sc = sc > 0.f ? sc : NEG_SLOPE * sc;
        m = fmaxf(m, sc);
    }
#pragma unroll
    for (int o = 32; o; o >>= 1) m = fmaxf(m, __shfl_xor(m, o));
    if (lane == 0) sm[w] = m;
    __syncthreads();
    m = fmaxf(sm[0], sm[1]);

    float den = 0.f;
    for (int i = row0 + tid; i < row1; i += 128) {
        int s = csr_src[i];
        float sc = ssrc[s] + sd;
        sc = sc > 0.f ? sc : NEG_SLOPE * sc;
        den += __expf(sc - m);
    }
#pragma unroll
    for (int o = 32; o; o >>= 1) den += __shfl_xor(den, o);
    if (lane == 0) sden[w] = den;
    __syncthreads();
    den = sden[0] + sden[1];
    const float rden = 1.f / (den + 1e-16f);

    float acc = 0.f;
    for (int i = row0; i < row1; ++i) {
        int s = csr_src[i];
        float sc = ssrc[s] + sd;
        sc = sc > 0.f ? sc : NEG_SLOPE * sc;
        acc += __expf(sc - m) * rden * h2[(size_t)s * 128 + tid];
    }
    float v = (acc + b[tid] - rm[tid]) * rsqrtf(rv[tid] + BN_EPS) * g[tid] + be[tid];
    out2[(size_t)n * 128 + tid] = v;   // BN2 applied; no activation
}

// ---------------- pooling ----------------
// thread j = channel; block = run of nodes; run-length atomics per graph
__global__ __launch_bounds__(128) void pool_kernel(const float* __restrict__ out2,
                                                   const int* __restrict__ batch,
                                                   float* __restrict__ pool,
                                                   int N, int npb) {
    const int j = threadIdx.x;
    int n0 = blockIdx.x * npb;
    int n1 = min(n0 + npb, N);
    if (n0 >= n1) return;
    int curg = batch[n0];
    float acc = 0.f;
    for (int n = n0; n < n1; ++n) {
        int gr = batch[n];
        if (gr != curg) {
            atomAddF(pool + (size_t)curg * 128 + j, acc);
            acc = 0.f; curg = gr;
        }
        acc += out2[(size_t)n * 128 + j];
    }
    atomAddF(pool + (size_t)curg * 128 + j, acc);
}

// count per graph via binary search on sorted batch (no atomics)
__device__ __forceinline__ int lowerBound(const int* __restrict__ a, int n, int v) {
    int lo = 0, hi = n;
    while (lo < hi) {
        int mid = (lo + hi) >> 1;
        if (a[mid] < v) lo = mid + 1; else hi = mid;
    }
    return lo;
}

__global__ __launch_bounds__(256) void final_kernel(const float* __restrict__ pool,
                                                    const int* __restrict__ batch,
                                                    float* __restrict__ out, int N) {
    int i = blockIdx.x * blockDim.x + threadIdx.x;  // 0..2047
    int g = i >> 7;
    int c = lowerBound(batch, N, g + 1) - lowerBound(batch, N, g);
    out[i] = pool[i] / fmaxf((float)c, 1.f);
}

extern "C" void kernel_launch(void* const* d_in, const int* in_sizes, int n_in,
                              void* d_out, int out_size, void* d_ws, size_t ws_size,
                              hipStream_t stream) {
    const float* x    = (const float*)d_in[0];
    const int* ei     = (const int*)d_in[1];
    const int* batch  = (const int*)d_in[2];
    const float* W1   = (const float*)d_in[3];
    const float* as1  = (const float*)d_in[4];
    const float* ad1  = (const float*)d_in[5];
    const float* b1   = (const float*)d_in[6];
    const float* g1   = (const float*)d_in[7];
    const float* be1  = (const float*)d_in[8];
    const float* rm1  = (const float*)d_in[9];
    const float* rv1  = (const float*)d_in[10];
    const float* W2   = (const float*)d_in[11];
    const float* as2  = (const float*)d_in[12];
    const float* ad2  = (const float*)d_in[13];
    const float* b2   = (const float*)d_in[14];
    const float* g2   = (const float*)d_in[15];
    const float* be2  = (const float*)d_in[16];
    const float* rm2  = (const float*)d_in[17];
    const float* rv2  = (const float*)d_in[18];
    float* out = (float*)d_out;

    const int N = in_sizes[0] / 128;   // 20000
    const int E = in_sizes[1] / 2;     // 640000
    const int Etot = E + N;            // self-loops appended
    const int* src = ei;
    const int* dst = ei + E;

    // workspace layout
    float* ws    = (float*)d_ws;
    float* h1    = ws;                               // N*256
    float* out1  = h1 + (size_t)N * 256;             // N*256
    float* out2  = out1 + (size_t)N * 256;           // N*128
    float* ssrc1 = out2 + (size_t)N * 128;           // N*4
    float* sdst1 = ssrc1 + (size_t)N * 4;            // N*4
    float* ssrc2 = sdst1 + (size_t)N * 4;            // N
    float* sdst2 = ssrc2 + N;                        // N
    float* pool  = sdst2 + N;                        // 16*128
    int*   deg   = (int*)(pool + 2048);              // N
    int*   rowptr= deg + N;                          // N+1
    int*   cursor= rowptr + N + 1;                   // N
    int*   csrs  = cursor + N;                       // Etot
    float* h2    = h1;                               // alias (h1 dead after fused1)

    const int eb = (Etot + 255) / 256;

    hipMemsetAsync(deg, 0, (size_t)N * sizeof(int), stream);
    hipMemsetAsync(pool, 0, 2048 * sizeof(float), stream);

    // ---- CSR build (by dst) ----
    deg_kernel<<<eb, 256, 0, stream>>>(dst, deg, E, Etot);
    scan_kernel<<<1, 256, 0, stream>>>(deg, rowptr, cursor, N);
    scatter_kernel<<<eb, 256, 0, stream>>>(src, dst, cursor, csrs, E, Etot);

    // ---- layer 1 ----
    gemm_kernel<<<dim3(256 / 64, (N + 63) / 64), 256, 0, stream>>>(x, W1, h1, N, 256, 128);
    score1_kernel<<<N, 256, 0, stream>>>(h1, as1, ad1, ssrc1, sdst1);
    fused1_kernel<<<N, 256, 0, stream>>>(csrs, rowptr, ssrc1, sdst1, h1,
                                         b1, g1, be1, rm1, rv1, out1);
    // ---- layer 2 (h1 dead; h2 aliases it) ----
    gemm_kernel<<<dim3(128 / 64, (N + 63) / 64), 256, 0, stream>>>(out1, W2, h2, N, 128, 256);
    score2_kernel<<<N / 4, 256, 0, stream>>>(h2, as2, ad2, ssrc2, sdst2);
    fused2_kernel<<<N, 128, 0, stream>>>(csrs, rowptr, ssrc2, sdst2, h2,
                                         b2, g2, be2, rm2, rv2, out2);

    // ---- pool ----
    pool_kernel<<<(N + 159) / 160, 128, 0, stream>>>(out2, batch, pool, N, 160);
    final_kernel<<<8, 256, 0, stream>>>(pool, batch, out, N);
}

// Round 4
// 528.095 us; speedup vs baseline: 2.9944x; 1.0966x over previous
//
#include <hip/hip_runtime.h>
#include <hip/hip_bf16.h>
#include <math.h>

#define NEG_SLOPE 0.2f
#define BN_EPS 1e-5f

typedef __attribute__((ext_vector_type(8))) short bf16x8;
typedef __attribute__((ext_vector_type(4))) float f32x4;

__device__ __forceinline__ void atomAddF(float* p, float v) { unsafeAtomicAdd(p, v); }

// ---------------- casts ----------------
__global__ __launch_bounds__(256) void castx_kernel(const float* __restrict__ in,
                                                    __hip_bfloat16* __restrict__ out, int n4) {
    int i = blockIdx.x * blockDim.x + threadIdx.x;
    if (i >= n4) return;
    float4 v = ((const float4*)in)[i];
    out[i * 4 + 0] = __float2bfloat16(v.x);
    out[i * 4 + 1] = __float2bfloat16(v.y);
    out[i * 4 + 2] = __float2bfloat16(v.z);
    out[i * 4 + 3] = __float2bfloat16(v.w);
}

// W [K,N] fp32 row-major -> WT [N,K] bf16 row-major
__global__ __launch_bounds__(256) void transw_kernel(const float* __restrict__ W,
                                                     __hip_bfloat16* __restrict__ WT,
                                                     int K, int N) {
    int i = blockIdx.x * blockDim.x + threadIdx.x;
    if (i >= K * N) return;
    int k = i / N, n = i - k * N;
    WT[(size_t)n * K + k] = __float2bfloat16(W[i]);
}

// ---------------- MFMA GEMM: C[M,N] = A[M,K] @ BT[N,K]^T, bf16 in/out -----------
// block 256 = 4 waves; tile 64x64; wave w -> rows 16w..16w+15, 4 col-tiles of 16
__global__ __launch_bounds__(256) void gemm_bf16_kernel(const __hip_bfloat16* __restrict__ A,
                                                        const __hip_bfloat16* __restrict__ BT,
                                                        __hip_bfloat16* __restrict__ C,
                                                        int M, int N, int K) {
    const int w = threadIdx.x >> 6;
    const int lane = threadIdx.x & 63;
    const int q = lane >> 4;          // 0..3
    const int r16 = lane & 15;
    const int bm = blockIdx.y * 64;
    const int bn = blockIdx.x * 64;
    const int am = bm + w * 16 + r16;
    const int ama = am < M ? am : M - 1;
    f32x4 acc[4] = {};
    for (int k0 = 0; k0 < K; k0 += 32) {
        bf16x8 a = *(const bf16x8*)(A + (size_t)ama * K + k0 + q * 8);
#pragma unroll
        for (int t = 0; t < 4; ++t) {
            bf16x8 b = *(const bf16x8*)(BT + (size_t)(bn + t * 16 + r16) * K + k0 + q * 8);
            acc[t] = __builtin_amdgcn_mfma_f32_16x16x32_bf16(a, b, acc[t], 0, 0, 0);
        }
    }
#pragma unroll
    for (int t = 0; t < 4; ++t)
#pragma unroll
        for (int r = 0; r < 4; ++r) {
            int row = bm + w * 16 + q * 4 + r;
            if (row < M)
                C[(size_t)row * N + bn + t * 16 + r16] = __float2bfloat16(acc[t][r]);
        }
}

// ---------------- CSR build ----------------
__global__ __launch_bounds__(256) void deg_kernel(const int* __restrict__ dst,
                                                  int* __restrict__ deg, int E, int Etot) {
    int e = blockIdx.x * blockDim.x + threadIdx.x;
    if (e >= Etot) return;
    int d = (e < E) ? dst[e] : e - E;
    atomicAdd(deg + d, 1);
}

__global__ __launch_bounds__(256) void scan_kernel(const int* __restrict__ deg,
                                                   int* __restrict__ rowptr,
                                                   int* __restrict__ cursor, int N) {
    __shared__ int sums[256];
    const int t = threadIdx.x;
    const int chunk = (N + 255) / 256;
    const int s0 = t * chunk, s1 = min(s0 + chunk, N);
    int sum = 0;
    for (int i = s0; i < s1; ++i) sum += deg[i];
    sums[t] = sum;
    __syncthreads();
    if (t == 0) {
        int acc = 0;
        for (int i = 0; i < 256; ++i) { int v = sums[i]; sums[i] = acc; acc += v; }
        rowptr[N] = acc;
    }
    __syncthreads();
    int acc = sums[t];
    for (int i = s0; i < s1; ++i) { rowptr[i] = acc; cursor[i] = acc; acc += deg[i]; }
}

__global__ __launch_bounds__(256) void scatter_kernel(const int* __restrict__ src,
                                                      const int* __restrict__ dst,
                                                      int* __restrict__ cursor,
                                                      int* __restrict__ csr_src,
                                                      int E, int Etot) {
    int e = blockIdx.x * blockDim.x + threadIdx.x;
    if (e >= Etot) return;
    int s, d;
    if (e < E) { s = src[e]; d = dst[e]; } else { s = d = e - E; }
    int pos = atomicAdd(cursor + d, 1);
    csr_src[pos] = s;
}

// ---------------- Layer 1 scores ----------------
__global__ __launch_bounds__(256) void score1_kernel(const __hip_bfloat16* __restrict__ h1,
                                                     const float* __restrict__ asrc,
                                                     const float* __restrict__ adst,
                                                     float* __restrict__ ssrc,
                                                     float* __restrict__ sdst) {
    const int n = blockIdx.x;
    const int tid = threadIdx.x;       // == h*64 + c
    float v = __bfloat162float(h1[(size_t)n * 256 + tid]);
    float ps = v * asrc[tid];
    float pd = v * adst[tid];
#pragma unroll
    for (int o = 32; o; o >>= 1) { ps += __shfl_down(ps, o); pd += __shfl_down(pd, o); }
    const int lane = tid & 63, w = tid >> 6;
    if (lane == 0) { ssrc[n * 4 + w] = ps; sdst[n * 4 + w] = pd; }
}

// ---------------- Layer 1 fused: softmax + aggregate + bias + BN + ELU ----------
// block = dst node, tid = h*64 + lane; wave h handles head h
// ex layout: [h][Etot] so pass-2 stores are dense per wave
__global__ __launch_bounds__(256) void fused1_kernel(const int* __restrict__ csr_src,
                                                     const int* __restrict__ rowptr,
                                                     const float* __restrict__ ssrc,
                                                     const float* __restrict__ sdst,
                                                     const __hip_bfloat16* __restrict__ h1,
                                                     float* __restrict__ ex,
                                                     const float* __restrict__ b,
                                                     const float* __restrict__ g,
                                                     const float* __restrict__ be,
                                                     const float* __restrict__ rm,
                                                     const float* __restrict__ rv,
                                                     __hip_bfloat16* __restrict__ out1,
                                                     int Etot) {
    const int n = blockIdx.x;
    const int tid = threadIdx.x;
    const int h = tid >> 6, lane = tid & 63;
    const int row0 = rowptr[n], row1 = rowptr[n + 1];
    const float sd = sdst[n * 4 + h];
    float* exh = ex + (size_t)h * Etot;

    float m = -1e30f;
    for (int i = row0 + lane; i < row1; i += 64) {
        int s = csr_src[i];
        float sc = ssrc[s * 4 + h] + sd;
        sc = sc > 0.f ? sc : NEG_SLOPE * sc;
        m = fmaxf(m, sc);
    }
#pragma unroll
    for (int o = 32; o; o >>= 1) m = fmaxf(m, __shfl_xor(m, o));

    float den = 0.f;
    for (int i = row0 + lane; i < row1; i += 64) {
        int s = csr_src[i];
        float sc = ssrc[s * 4 + h] + sd;
        sc = sc > 0.f ? sc : NEG_SLOPE * sc;
        float e = __expf(sc - m);
        exh[i] = e;
        den += e;
    }
#pragma unroll
    for (int o = 32; o; o >>= 1) den += __shfl_xor(den, o);
    const float rden = 1.f / (den + 1e-16f);

    float acc = 0.f;
    for (int i = row0; i < row1; ++i) {
        int s = csr_src[i];                       // wave-uniform broadcast
        float al = exh[i];                        // broadcast 4B
        acc += al * __bfloat162float(h1[(size_t)s * 256 + tid]);
    }
    acc *= rden;
    float v = (acc + b[tid] - rm[tid]) * rsqrtf(rv[tid] + BN_EPS) * g[tid] + be[tid];
    out1[(size_t)n * 256 + tid] = __float2bfloat16(v > 0.f ? v : expm1f(v));
}

// ---------------- Layer 2 scores (1 head, 128 ch): 4 nodes/block ----------------
__global__ __launch_bounds__(256) void score2_kernel(const __hip_bfloat16* __restrict__ h2,
                                                     const float* __restrict__ asrc,
                                                     const float* __restrict__ adst,
                                                     float* __restrict__ ssrc,
                                                     float* __restrict__ sdst) {
    const int n = blockIdx.x * 4 + (threadIdx.x >> 6);
    const int lane = threadIdx.x & 63;
    float v0 = __bfloat162float(h2[(size_t)n * 128 + lane]);
    float v1 = __bfloat162float(h2[(size_t)n * 128 + 64 + lane]);
    float ps = v0 * asrc[lane] + v1 * asrc[64 + lane];
    float pd = v0 * adst[lane] + v1 * adst[64 + lane];
#pragma unroll
    for (int o = 32; o; o >>= 1) { ps += __shfl_down(ps, o); pd += __shfl_down(pd, o); }
    if (lane == 0) { ssrc[n] = ps; sdst[n] = pd; }
}

// ---------------- Layer 2 fused: softmax + aggregate + bias + BN2 ----------
__global__ __launch_bounds__(128) void fused2_kernel(const int* __restrict__ csr_src,
                                                     const int* __restrict__ rowptr,
                                                     const float* __restrict__ ssrc,
                                                     const float* __restrict__ sdst,
                                                     const __hip_bfloat16* __restrict__ h2,
                                                     float* __restrict__ ex,
                                                     const float* __restrict__ b,
                                                     const float* __restrict__ g,
                                                     const float* __restrict__ be,
                                                     const float* __restrict__ rm,
                                                     const float* __restrict__ rv,
                                                     float* __restrict__ out2) {
    const int n = blockIdx.x;
    const int tid = threadIdx.x;
    const int lane = tid & 63, w = tid >> 6;
    const int row0 = rowptr[n], row1 = rowptr[n + 1];
    const float sd = sdst[n];
    __shared__ float sm[2], sden[2];

    float m = -1e30f;
    for (int i = row0 + tid; i < row1; i += 128) {
        int s = csr_src[i];
        float sc = ssrc[s] + sd;
        sc = sc > 0.f ? sc : NEG_SLOPE * sc;
        m = fmaxf(m, sc);
    }
#pragma unroll
    for (int o = 32; o; o >>= 1) m = fmaxf(m, __shfl_xor(m, o));
    if (lane == 0) sm[w] = m;
    __syncthreads();
    m = fmaxf(sm[0], sm[1]);

    float den = 0.f;
    for (int i = row0 + tid; i < row1; i += 128) {
        int s = csr_src[i];
        float sc = ssrc[s] + sd;
        sc = sc > 0.f ? sc : NEG_SLOPE * sc;
        float e = __expf(sc - m);
        ex[i] = e;
        den += e;
    }
#pragma unroll
    for (int o = 32; o; o >>= 1) den += __shfl_xor(den, o);
    if (lane == 0) sden[w] = den;
    __syncthreads();
    den = sden[0] + sden[1];
    const float rden = 1.f / (den + 1e-16f);

    float acc = 0.f;
    for (int i = row0; i < row1; ++i) {
        int s = csr_src[i];
        acc += ex[i] * __bfloat162float(h2[(size_t)s * 128 + tid]);
    }
    acc *= rden;
    float v = (acc + b[tid] - rm[tid]) * rsqrtf(rv[tid] + BN_EPS) * g[tid] + be[tid];
    out2[(size_t)n * 128 + tid] = v;
}

// ---------------- pooling ----------------
__global__ __launch_bounds__(128) void pool_kernel(const float* __restrict__ out2,
                                                   const int* __restrict__ batch,
                                                   float* __restrict__ pool,
                                                   int N, int npb) {
    const int j = threadIdx.x;
    int n0 = blockIdx.x * npb;
    int n1 = min(n0 + npb, N);
    if (n0 >= n1) return;
    int curg = batch[n0];
    float acc = 0.f;
    for (int n = n0; n < n1; ++n) {
        int gr = batch[n];
        if (gr != curg) {
            atomAddF(pool + (size_t)curg * 128 + j, acc);
            acc = 0.f; curg = gr;
        }
        acc += out2[(size_t)n * 128 + j];
    }
    atomAddF(pool + (size_t)curg * 128 + j, acc);
}

__device__ __forceinline__ int lowerBound(const int* __restrict__ a, int n, int v) {
    int lo = 0, hi = n;
    while (lo < hi) {
        int mid = (lo + hi) >> 1;
        if (a[mid] < v) lo = mid + 1; else hi = mid;
    }
    return lo;
}

__global__ __launch_bounds__(256) void final_kernel(const float* __restrict__ pool,
                                                    const int* __restrict__ batch,
                                                    float* __restrict__ out, int N) {
    int i = blockIdx.x * blockDim.x + threadIdx.x;  // 0..2047
    int g = i >> 7;
    int c = lowerBound(batch, N, g + 1) - lowerBound(batch, N, g);
    out[i] = pool[i] / fmaxf((float)c, 1.f);
}

extern "C" void kernel_launch(void* const* d_in, const int* in_sizes, int n_in,
                              void* d_out, int out_size, void* d_ws, size_t ws_size,
                              hipStream_t stream) {
    const float* x    = (const float*)d_in[0];
    const int* ei     = (const int*)d_in[1];
    const int* batch  = (const int*)d_in[2];
    const float* W1   = (const float*)d_in[3];
    const float* as1  = (const float*)d_in[4];
    const float* ad1  = (const float*)d_in[5];
    const float* b1   = (const float*)d_in[6];
    const float* g1   = (const float*)d_in[7];
    const float* be1  = (const float*)d_in[8];
    const float* rm1  = (const float*)d_in[9];
    const float* rv1  = (const float*)d_in[10];
    const float* W2   = (const float*)d_in[11];
    const float* as2  = (const float*)d_in[12];
    const float* ad2  = (const float*)d_in[13];
    const float* b2   = (const float*)d_in[14];
    const float* g2   = (const float*)d_in[15];
    const float* be2  = (const float*)d_in[16];
    const float* rm2  = (const float*)d_in[17];
    const float* rv2  = (const float*)d_in[18];
    float* out = (float*)d_out;

    const int N = in_sizes[0] / 128;   // 20000
    const int E = in_sizes[1] / 2;     // 640000
    const int Etot = E + N;
    const int* src = ei;
    const int* dst = ei + E;

    // workspace carve (256B-aligned)
    char* p = (char*)d_ws;
    auto alloc = [&](size_t bytes) { char* r = p; p += (bytes + 255) & ~(size_t)255; return r; };
    __hip_bfloat16* h1   = (__hip_bfloat16*)alloc((size_t)N * 256 * 2);
    __hip_bfloat16* out1 = (__hip_bfloat16*)alloc((size_t)N * 256 * 2);
    float* out2          = (float*)alloc((size_t)N * 128 * 4);
    __hip_bfloat16* xbf  = (__hip_bfloat16*)alloc((size_t)N * 128 * 2);
    __hip_bfloat16* WT1  = (__hip_bfloat16*)alloc(256 * 128 * 2);
    __hip_bfloat16* WT2  = (__hip_bfloat16*)alloc(128 * 256 * 2);
    float* ssrc1         = (float*)alloc((size_t)N * 4 * 4);
    float* sdst1         = (float*)alloc((size_t)N * 4 * 4);
    float* ssrc2         = (float*)alloc((size_t)N * 4);
    float* sdst2         = (float*)alloc((size_t)N * 4);
    float* pool          = (float*)alloc(2048 * 4);
    int*   deg           = (int*)alloc((size_t)N * 4);
    int*   rowptr        = (int*)alloc((size_t)(N + 1) * 4);
    int*   cursor        = (int*)alloc((size_t)N * 4);
    int*   csrs          = (int*)alloc((size_t)Etot * 4);
    float* ex            = (float*)alloc((size_t)Etot * 4 * 4);  // [4][Etot] L1; L2 reuses [0]
    __hip_bfloat16* h2   = h1;   // alias (h1 dead after fused1)

    const int eb = (Etot + 255) / 256;

    hipMemsetAsync(deg, 0, (size_t)N * sizeof(int), stream);
    hipMemsetAsync(pool, 0, 2048 * sizeof(float), stream);

    // ---- casts + CSR build ----
    castx_kernel<<<(N * 128 / 4 + 255) / 256, 256, 0, stream>>>(x, xbf, N * 128 / 4);
    transw_kernel<<<(128 * 256 + 255) / 256, 256, 0, stream>>>(W1, WT1, 128, 256);
    transw_kernel<<<(256 * 128 + 255) / 256, 256, 0, stream>>>(W2, WT2, 256, 128);
    deg_kernel<<<eb, 256, 0, stream>>>(dst, deg, E, Etot);
    scan_kernel<<<1, 256, 0, stream>>>(deg, rowptr, cursor, N);
    scatter_kernel<<<eb, 256, 0, stream>>>(src, dst, cursor, csrs, E, Etot);

    // ---- layer 1 ----
    gemm_bf16_kernel<<<dim3(256 / 64, (N + 63) / 64), 256, 0, stream>>>(xbf, WT1, h1, N, 256, 128);
    score1_kernel<<<N, 256, 0, stream>>>(h1, as1, ad1, ssrc1, sdst1);
    fused1_kernel<<<N, 256, 0, stream>>>(csrs, rowptr, ssrc1, sdst1, h1, ex,
                                         b1, g1, be1, rm1, rv1, out1, Etot);
    // ---- layer 2 ----
    gemm_bf16_kernel<<<dim3(128 / 64, (N + 63) / 64), 256, 0, stream>>>(out1, WT2, h2, N, 128, 256);
    score2_kernel<<<N / 4, 256, 0, stream>>>(h2, as2, ad2, ssrc2, sdst2);
    fused2_kernel<<<N, 128, 0, stream>>>(csrs, rowptr, ssrc2, sdst2, h2, ex,
                                         b2, g2, be2, rm2, rv2, out2);

    // ---- pool ----
    pool_kernel<<<(N + 159) / 160, 128, 0, stream>>>(out2, batch, pool, N, 160);
    final_kernel<<<8, 256, 0, stream>>>(pool, batch, out, N);
}

// Round 5
// 408.812 us; speedup vs baseline: 3.8681x; 1.2918x over previous
//
#include <hip/hip_runtime.h>
#include <hip/hip_bf16.h>
#include <math.h>

#define NEG_SLOPE 0.2f
#define BN_EPS 1e-5f

typedef __attribute__((ext_vector_type(8))) short bf16x8;
typedef __attribute__((ext_vector_type(4))) float f32x4;

__device__ __forceinline__ void atomAddF(float* p, float v) { unsafeAtomicAdd(p, v); }

// ---------------- casts ----------------
__global__ __launch_bounds__(256) void castx_kernel(const float* __restrict__ in,
                                                    __hip_bfloat16* __restrict__ out, int n4) {
    int i = blockIdx.x * blockDim.x + threadIdx.x;
    if (i >= n4) return;
    float4 v = ((const float4*)in)[i];
    out[i * 4 + 0] = __float2bfloat16(v.x);
    out[i * 4 + 1] = __float2bfloat16(v.y);
    out[i * 4 + 2] = __float2bfloat16(v.z);
    out[i * 4 + 3] = __float2bfloat16(v.w);
}

// W [K,N] fp32 row-major -> WT [N,K] bf16 row-major
__global__ __launch_bounds__(256) void transw_kernel(const float* __restrict__ W,
                                                     __hip_bfloat16* __restrict__ WT,
                                                     int K, int N) {
    int i = blockIdx.x * blockDim.x + threadIdx.x;
    if (i >= K * N) return;
    int k = i / N, n = i - k * N;
    WT[(size_t)n * K + k] = __float2bfloat16(W[i]);
}

// ---------------- MFMA GEMM: C[M,N] = A[M,K] @ BT[N,K]^T, bf16 in/out -----------
__global__ __launch_bounds__(256) void gemm_bf16_kernel(const __hip_bfloat16* __restrict__ A,
                                                        const __hip_bfloat16* __restrict__ BT,
                                                        __hip_bfloat16* __restrict__ C,
                                                        int M, int N, int K) {
    const int w = threadIdx.x >> 6;
    const int lane = threadIdx.x & 63;
    const int q = lane >> 4;          // 0..3
    const int r16 = lane & 15;
    const int bm = blockIdx.y * 64;
    const int bn = blockIdx.x * 64;
    const int am = bm + w * 16 + r16;
    const int ama = am < M ? am : M - 1;
    f32x4 acc[4] = {};
    for (int k0 = 0; k0 < K; k0 += 32) {
        bf16x8 a = *(const bf16x8*)(A + (size_t)ama * K + k0 + q * 8);
#pragma unroll
        for (int t = 0; t < 4; ++t) {
            bf16x8 b = *(const bf16x8*)(BT + (size_t)(bn + t * 16 + r16) * K + k0 + q * 8);
            acc[t] = __builtin_amdgcn_mfma_f32_16x16x32_bf16(a, b, acc[t], 0, 0, 0);
        }
    }
#pragma unroll
    for (int t = 0; t < 4; ++t)
#pragma unroll
        for (int r = 0; r < 4; ++r) {
            int row = bm + w * 16 + q * 4 + r;
            if (row < M)
                C[(size_t)row * N + bn + t * 16 + r16] = __float2bfloat16(acc[t][r]);
        }
}

// ---------------- CSR build ----------------
__global__ __launch_bounds__(256) void deg_kernel(const int* __restrict__ dst,
                                                  int* __restrict__ deg, int E, int Etot) {
    int e = blockIdx.x * blockDim.x + threadIdx.x;
    if (e >= Etot) return;
    int d = (e < E) ? dst[e] : e - E;
    atomicAdd(deg + d, 1);
}

// 1024-thread parallel scan: per-thread chunk sum -> wave shfl scan -> LDS scan of 16
__global__ __launch_bounds__(1024) void scan_kernel(const int* __restrict__ deg,
                                                    int* __restrict__ rowptr,
                                                    int* __restrict__ cursor, int N) {
    __shared__ int wsum[16];
    const int t = threadIdx.x;
    const int chunk = (N + 1023) / 1024;
    const int s0 = min(t * chunk, N), s1 = min(s0 + chunk, N);
    int sum = 0;
    for (int i = s0; i < s1; ++i) sum += deg[i];
    const int lane = t & 63, w = t >> 6;
    int v = sum;
#pragma unroll
    for (int o = 1; o < 64; o <<= 1) {
        int u = __shfl_up(v, o);
        if (lane >= o) v += u;
    }
    if (lane == 63) wsum[w] = v;
    __syncthreads();
    if (t < 16) {
        int xv = wsum[t];
#pragma unroll
        for (int o = 1; o < 16; o <<= 1) {
            int u = __shfl_up(xv, o);
            if (t >= o) xv += u;
        }
        wsum[t] = xv;
    }
    __syncthreads();
    int excl = v - sum + (w ? wsum[w - 1] : 0);
    int acc = excl;
    for (int i = s0; i < s1; ++i) { rowptr[i] = acc; cursor[i] = acc; acc += deg[i]; }
    if (s1 == N && s0 < N) rowptr[N] = acc;
}

__global__ __launch_bounds__(256) void scatter_kernel(const int* __restrict__ src,
                                                      const int* __restrict__ dst,
                                                      int* __restrict__ cursor,
                                                      int* __restrict__ csr_src,
                                                      int E, int Etot) {
    int e = blockIdx.x * blockDim.x + threadIdx.x;
    if (e >= Etot) return;
    int s, d;
    if (e < E) { s = src[e]; d = dst[e]; } else { s = d = e - E; }
    int pos = atomicAdd(cursor + d, 1);
    csr_src[pos] = s;
}

// ---------------- Layer 1 scores ----------------
__global__ __launch_bounds__(256) void score1_kernel(const __hip_bfloat16* __restrict__ h1,
                                                     const float* __restrict__ asrc,
                                                     const float* __restrict__ adst,
                                                     float* __restrict__ ssrc,
                                                     float* __restrict__ sdst) {
    const int n = blockIdx.x;
    const int tid = threadIdx.x;       // == h*64 + c
    float v = __bfloat162float(h1[(size_t)n * 256 + tid]);
    float ps = v * asrc[tid];
    float pd = v * adst[tid];
#pragma unroll
    for (int o = 32; o; o >>= 1) { ps += __shfl_down(ps, o); pd += __shfl_down(pd, o); }
    const int lane = tid & 63, w = tid >> 6;
    if (lane == 0) { ssrc[n * 4 + w] = ps; sdst[n * 4 + w] = pd; }
}

// ---------------- Layer 1 fused: softmax + aggregate + bias + BN + ELU ----------
// block = dst node, tid = h*64 + lane; wave h handles head h
__global__ __launch_bounds__(256) void fused1_kernel(const int* __restrict__ csr_src,
                                                     const int* __restrict__ rowptr,
                                                     const float* __restrict__ ssrc,
                                                     const float* __restrict__ sdst,
                                                     const __hip_bfloat16* __restrict__ h1,
                                                     float* __restrict__ ex,
                                                     const float* __restrict__ b,
                                                     const float* __restrict__ g,
                                                     const float* __restrict__ be,
                                                     const float* __restrict__ rm,
                                                     const float* __restrict__ rv,
                                                     __hip_bfloat16* __restrict__ out1,
                                                     int Etot) {
    const int n = blockIdx.x;
    const int tid = threadIdx.x;
    const int h = tid >> 6, lane = tid & 63;
    const int row0 = rowptr[n], row1 = rowptr[n + 1];
    const float sd = sdst[n * 4 + h];
    float* exh = ex + (size_t)h * Etot;

    float m = -1e30f;
    for (int i = row0 + lane; i < row1; i += 64) {
        int s = csr_src[i];
        float sc = ssrc[s * 4 + h] + sd;
        sc = sc > 0.f ? sc : NEG_SLOPE * sc;
        m = fmaxf(m, sc);
    }
#pragma unroll
    for (int o = 32; o; o >>= 1) m = fmaxf(m, __shfl_xor(m, o));

    float den = 0.f;
    for (int i = row0 + lane; i < row1; i += 64) {
        int s = csr_src[i];
        float sc = ssrc[s * 4 + h] + sd;
        sc = sc > 0.f ? sc : NEG_SLOPE * sc;
        float e = __expf(sc - m);
        exh[i] = e;
        den += e;
    }
#pragma unroll
    for (int o = 32; o; o >>= 1) den += __shfl_xor(den, o);
    const float rden = 1.f / (den + 1e-16f);

    // unroll-8 aggregation: 8 independent row gathers in flight per wave
    float acc = 0.f;
    int i = row0;
    const int cnt8 = (row1 - row0) & ~7;
    for (; i < row0 + cnt8; i += 8) {
        int s[8]; float a[8], hv[8];
#pragma unroll
        for (int u = 0; u < 8; ++u) { s[u] = csr_src[i + u]; a[u] = exh[i + u]; }
#pragma unroll
        for (int u = 0; u < 8; ++u)
            hv[u] = __bfloat162float(h1[(size_t)s[u] * 256 + tid]);
#pragma unroll
        for (int u = 0; u < 8; ++u) acc += a[u] * hv[u];
    }
    for (; i < row1; ++i)
        acc += exh[i] * __bfloat162float(h1[(size_t)csr_src[i] * 256 + tid]);
    acc *= rden;

    float v = (acc + b[tid] - rm[tid]) * rsqrtf(rv[tid] + BN_EPS) * g[tid] + be[tid];
    out1[(size_t)n * 256 + tid] = __float2bfloat16(v > 0.f ? v : expm1f(v));
}

// ---------------- Layer 2 scores (1 head, 128 ch): 4 nodes/block ----------------
__global__ __launch_bounds__(256) void score2_kernel(const __hip_bfloat16* __restrict__ h2,
                                                     const float* __restrict__ asrc,
                                                     const float* __restrict__ adst,
                                                     float* __restrict__ ssrc,
                                                     float* __restrict__ sdst) {
    const int n = blockIdx.x * 4 + (threadIdx.x >> 6);
    const int lane = threadIdx.x & 63;
    float v0 = __bfloat162float(h2[(size_t)n * 128 + lane]);
    float v1 = __bfloat162float(h2[(size_t)n * 128 + 64 + lane]);
    float ps = v0 * asrc[lane] + v1 * asrc[64 + lane];
    float pd = v0 * adst[lane] + v1 * adst[64 + lane];
#pragma unroll
    for (int o = 32; o; o >>= 1) { ps += __shfl_down(ps, o); pd += __shfl_down(pd, o); }
    if (lane == 0) { ssrc[n] = ps; sdst[n] = pd; }
}

// ---------------- Layer 2 fused: softmax + aggregate + bias + BN2 ----------
__global__ __launch_bounds__(128) void fused2_kernel(const int* __restrict__ csr_src,
                                                     const int* __restrict__ rowptr,
                                                     const float* __restrict__ ssrc,
                                                     const float* __restrict__ sdst,
                                                     const __hip_bfloat16* __restrict__ h2,
                                                     float* __restrict__ ex,
                                                     const float* __restrict__ b,
                                                     const float* __restrict__ g,
                                                     const float* __restrict__ be,
                                                     const float* __restrict__ rm,
                                                     const float* __restrict__ rv,
                                                     float* __restrict__ out2) {
    const int n = blockIdx.x;
    const int tid = threadIdx.x;
    const int lane = tid & 63, w = tid >> 6;
    const int row0 = rowptr[n], row1 = rowptr[n + 1];
    const float sd = sdst[n];
    __shared__ float sm[2], sden[2];

    float m = -1e30f;
    for (int i = row0 + tid; i < row1; i += 128) {
        int s = csr_src[i];
        float sc = ssrc[s] + sd;
        sc = sc > 0.f ? sc : NEG_SLOPE * sc;
        m = fmaxf(m, sc);
    }
#pragma unroll
    for (int o = 32; o; o >>= 1) m = fmaxf(m, __shfl_xor(m, o));
    if (lane == 0) sm[w] = m;
    __syncthreads();
    m = fmaxf(sm[0], sm[1]);

    float den = 0.f;
    for (int i = row0 + tid; i < row1; i += 128) {
        int s = csr_src[i];
        float sc = ssrc[s] + sd;
        sc = sc > 0.f ? sc : NEG_SLOPE * sc;
        float e = __expf(sc - m);
        ex[i] = e;
        den += e;
    }
#pragma unroll
    for (int o = 32; o; o >>= 1) den += __shfl_xor(den, o);
    if (lane == 0) sden[w] = den;
    __syncthreads();
    den = sden[0] + sden[1];
    const float rden = 1.f / (den + 1e-16f);

    float acc = 0.f;
    int i = row0;
    const int cnt8 = (row1 - row0) & ~7;
    for (; i < row0 + cnt8; i += 8) {
        int s[8]; float a[8], hv[8];
#pragma unroll
        for (int u = 0; u < 8; ++u) { s[u] = csr_src[i + u]; a[u] = ex[i + u]; }
#pragma unroll
        for (int u = 0; u < 8; ++u)
            hv[u] = __bfloat162float(h2[(size_t)s[u] * 128 + tid]);
#pragma unroll
        for (int u = 0; u < 8; ++u) acc += a[u] * hv[u];
    }
    for (; i < row1; ++i)
        acc += ex[i] * __bfloat162float(h2[(size_t)csr_src[i] * 128 + tid]);
    acc *= rden;

    float v = (acc + b[tid] - rm[tid]) * rsqrtf(rv[tid] + BN_EPS) * g[tid] + be[tid];
    out2[(size_t)n * 128 + tid] = v;
}

// ---------------- pooling ----------------
__global__ __launch_bounds__(128) void pool_kernel(const float* __restrict__ out2,
                                                   const int* __restrict__ batch,
                                                   float* __restrict__ pool,
                                                   int N, int npb) {
    const int j = threadIdx.x;
    int n0 = blockIdx.x * npb;
    int n1 = min(n0 + npb, N);
    if (n0 >= n1) return;
    int curg = batch[n0];
    float acc = 0.f;
    for (int n = n0; n < n1; ++n) {
        int gr = batch[n];
        if (gr != curg) {
            atomAddF(pool + (size_t)curg * 128 + j, acc);
            acc = 0.f; curg = gr;
        }
        acc += out2[(size_t)n * 128 + j];
    }
    atomAddF(pool + (size_t)curg * 128 + j, acc);
}

__device__ __forceinline__ int lowerBound(const int* __restrict__ a, int n, int v) {
    int lo = 0, hi = n;
    while (lo < hi) {
        int mid = (lo + hi) >> 1;
        if (a[mid] < v) lo = mid + 1; else hi = mid;
    }
    return lo;
}

__global__ __launch_bounds__(256) void final_kernel(const float* __restrict__ pool,
                                                    const int* __restrict__ batch,
                                                    float* __restrict__ out, int N) {
    int i = blockIdx.x * blockDim.x + threadIdx.x;  // 0..2047
    int g = i >> 7;
    int c = lowerBound(batch, N, g + 1) - lowerBound(batch, N, g);
    out[i] = pool[i] / fmaxf((float)c, 1.f);
}

extern "C" void kernel_launch(void* const* d_in, const int* in_sizes, int n_in,
                              void* d_out, int out_size, void* d_ws, size_t ws_size,
                              hipStream_t stream) {
    const float* x    = (const float*)d_in[0];
    const int* ei     = (const int*)d_in[1];
    const int* batch  = (const int*)d_in[2];
    const float* W1   = (const float*)d_in[3];
    const float* as1  = (const float*)d_in[4];
    const float* ad1  = (const float*)d_in[5];
    const float* b1   = (const float*)d_in[6];
    const float* g1   = (const float*)d_in[7];
    const float* be1  = (const float*)d_in[8];
    const float* rm1  = (const float*)d_in[9];
    const float* rv1  = (const float*)d_in[10];
    const float* W2   = (const float*)d_in[11];
    const float* as2  = (const float*)d_in[12];
    const float* ad2  = (const float*)d_in[13];
    const float* b2   = (const float*)d_in[14];
    const float* g2   = (const float*)d_in[15];
    const float* be2  = (const float*)d_in[16];
    const float* rm2  = (const float*)d_in[17];
    const float* rv2  = (const float*)d_in[18];
    float* out = (float*)d_out;

    const int N = in_sizes[0] / 128;   // 20000
    const int E = in_sizes[1] / 2;     // 640000
    const int Etot = E + N;
    const int* src = ei;
    const int* dst = ei + E;

    // workspace carve (256B-aligned)
    char* p = (char*)d_ws;
    auto alloc = [&](size_t bytes) { char* r = p; p += (bytes + 255) & ~(size_t)255; return r; };
    __hip_bfloat16* h1   = (__hip_bfloat16*)alloc((size_t)N * 256 * 2);
    __hip_bfloat16* out1 = (__hip_bfloat16*)alloc((size_t)N * 256 * 2);
    float* out2          = (float*)alloc((size_t)N * 128 * 4);
    __hip_bfloat16* xbf  = (__hip_bfloat16*)alloc((size_t)N * 128 * 2);
    __hip_bfloat16* WT1  = (__hip_bfloat16*)alloc(256 * 128 * 2);
    __hip_bfloat16* WT2  = (__hip_bfloat16*)alloc(128 * 256 * 2);
    float* ssrc1         = (float*)alloc((size_t)N * 4 * 4);
    float* sdst1         = (float*)alloc((size_t)N * 4 * 4);
    float* ssrc2         = (float*)alloc((size_t)N * 4);
    float* sdst2         = (float*)alloc((size_t)N * 4);
    float* pool          = (float*)alloc(2048 * 4);
    int*   deg           = (int*)alloc((size_t)N * 4);
    int*   rowptr        = (int*)alloc((size_t)(N + 1) * 4);
    int*   cursor        = (int*)alloc((size_t)N * 4);
    int*   csrs          = (int*)alloc((size_t)Etot * 4);
    float* ex            = (float*)alloc((size_t)Etot * 4 * 4);  // [4][Etot] L1; L2 reuses [0]
    __hip_bfloat16* h2   = h1;   // alias (h1 dead after fused1)

    const int eb = (Etot + 255) / 256;

    hipMemsetAsync(deg, 0, (size_t)N * sizeof(int), stream);
    hipMemsetAsync(pool, 0, 2048 * sizeof(float), stream);

    // ---- casts + CSR build ----
    castx_kernel<<<(N * 128 / 4 + 255) / 256, 256, 0, stream>>>(x, xbf, N * 128 / 4);
    transw_kernel<<<(128 * 256 + 255) / 256, 256, 0, stream>>>(W1, WT1, 128, 256);
    transw_kernel<<<(256 * 128 + 255) / 256, 256, 0, stream>>>(W2, WT2, 256, 128);
    deg_kernel<<<eb, 256, 0, stream>>>(dst, deg, E, Etot);
    scan_kernel<<<1, 1024, 0, stream>>>(deg, rowptr, cursor, N);
    scatter_kernel<<<eb, 256, 0, stream>>>(src, dst, cursor, csrs, E, Etot);

    // ---- layer 1 ----
    gemm_bf16_kernel<<<dim3(256 / 64, (N + 63) / 64), 256, 0, stream>>>(xbf, WT1, h1, N, 256, 128);
    score1_kernel<<<N, 256, 0, stream>>>(h1, as1, ad1, ssrc1, sdst1);
    fused1_kernel<<<N, 256, 0, stream>>>(csrs, rowptr, ssrc1, sdst1, h1, ex,
                                         b1, g1, be1, rm1, rv1, out1, Etot);
    // ---- layer 2 ----
    gemm_bf16_kernel<<<dim3(128 / 64, (N + 63) / 64), 256, 0, stream>>>(out1, WT2, h2, N, 128, 256);
    score2_kernel<<<N / 4, 256, 0, stream>>>(h2, as2, ad2, ssrc2, sdst2);
    fused2_kernel<<<N, 128, 0, stream>>>(csrs, rowptr, ssrc2, sdst2, h2, ex,
                                         b2, g2, be2, rm2, rv2, out2);

    // ---- pool ----
    pool_kernel<<<(N + 159) / 160, 128, 0, stream>>>(out2, batch, pool, N, 160);
    final_kernel<<<8, 256, 0, stream>>>(pool, batch, out, N);
}